// Round 7
// baseline (92.591 us; speedup 1.0000x reference)
//
#include <hip/hip_runtime.h>
#include <hip/hip_bf16.h>

#define B_ROWS 4096
#define N2 8192
#define DD 512
#define NBT 32       // 8192/256 tile-blocks per dim
#define NTRI 528     // NBT*(NBT+1)/2
#define NT 8         // DD/64 K-tiles

typedef __attribute__((ext_vector_type(8))) short short8v;
typedef __attribute__((ext_vector_type(4))) float float4v;

__device__ inline unsigned int f2bf(float f) {
  unsigned int u = __float_as_uint(f);
  u += 0x7fffu + ((u >> 16) & 1u);
  return u >> 16;
}

// ---------- normalize + targets + rowsum-zero, one wave per row-pair ----------
__global__ __launch_bounds__(256) void k_norm_tgt(const float* __restrict__ f1,
                                                  const float* __restrict__ f2,
                                                  uint4* __restrict__ zn,
                                                  float* __restrict__ tpart,
                                                  float* __restrict__ rowsum) {
  int w = threadIdx.x >> 6, lane = threadIdx.x & 63;
  int j = blockIdx.x * 4 + w;  // pair index 0..4095
  const float4* s1 = (const float4*)(f1 + (size_t)j * DD);
  const float4* s2 = (const float4*)(f2 + (size_t)j * DD);
  float4 a0 = s1[lane * 2], a1 = s1[lane * 2 + 1];
  float4 b0 = s2[lane * 2], b1 = s2[lane * 2 + 1];
  float ss1 = a0.x * a0.x + a0.y * a0.y + a0.z * a0.z + a0.w * a0.w +
              a1.x * a1.x + a1.y * a1.y + a1.z * a1.z + a1.w * a1.w;
  float ss2 = b0.x * b0.x + b0.y * b0.y + b0.z * b0.z + b0.w * b0.w +
              b1.x * b1.x + b1.y * b1.y + b1.z * b1.z + b1.w * b1.w;
  float ab = a0.x * b0.x + a0.y * b0.y + a0.z * b0.z + a0.w * b0.w +
             a1.x * b1.x + a1.y * b1.y + a1.z * b1.z + a1.w * b1.w;
#pragma unroll
  for (int o = 1; o < 64; o <<= 1) {
    ss1 += __shfl_xor(ss1, o, 64);
    ss2 += __shfl_xor(ss2, o, 64);
    ab += __shfl_xor(ab, o, 64);
  }
  float inv1 = 1.0f / fmaxf(sqrtf(ss1), 1e-8f);
  float inv2 = 1.0f / fmaxf(sqrtf(ss2), 1e-8f);
  uint4 p;
  p.x = f2bf(a0.x * inv1) | (f2bf(a0.y * inv1) << 16);
  p.y = f2bf(a0.z * inv1) | (f2bf(a0.w * inv1) << 16);
  p.z = f2bf(a1.x * inv1) | (f2bf(a1.y * inv1) << 16);
  p.w = f2bf(a1.z * inv1) | (f2bf(a1.w * inv1) << 16);
  zn[(size_t)j * (DD / 8) + lane] = p;
  p.x = f2bf(b0.x * inv2) | (f2bf(b0.y * inv2) << 16);
  p.y = f2bf(b0.z * inv2) | (f2bf(b0.w * inv2) << 16);
  p.z = f2bf(b1.x * inv2) | (f2bf(b1.y * inv2) << 16);
  p.w = f2bf(b1.z * inv2) | (f2bf(b1.w * inv2) << 16);
  zn[(size_t)(B_ROWS + j) * (DD / 8) + lane] = p;
  if (lane == 0) tpart[j] = 2.0f + 2.0f * ab * inv1 * inv2;  // logit[i,i] + logit[i,i+B]
  if (threadIdx.x < 8) rowsum[blockIdx.x * 8 + threadIdx.x] = 0.f;  // 1024*8 = 8192
}

// ---------- main: upper-triangular 256x256 tiles, band-major + 8-wave phase schedule ----------
__global__ __launch_bounds__(512, 2) void k_gemm_expsum(const unsigned short* __restrict__ zn,
                                                        float* __restrict__ rowsum) {
  __shared__ __align__(16) char smem[131072];  // [buf:2][A 32KB | B 32KB]

  // XCD-chunked swizzle (528 % 8 == 0), then band-major decode (bands of 8 bj)
  int g = (blockIdx.x & 7) * (NTRI / 8) + (blockIdx.x >> 3);
  int b = 3;
  while (32 * b * b + 4 * b > g) --b;        // off(b) = 32b^2 + 4b
  int tp = g - (32 * b * b + 4 * b);
  int bi, bj;
  if (tp < 64 * b) {
    bi = tp >> 3;                 // A panel reused for 8 consecutive tiles
    bj = 8 * b + (tp & 7);        // B window: 8 panels (2 MB), L2-hot
  } else {
    int u = tp - 64 * b;          // 0..35: upper-tri of the 8x8 diagonal block
    int r = 0;
    while ((r + 1) * 8 - (r * (r + 1)) / 2 <= u) ++r;
    int before = r * 8 - ((r - 1) * r) / 2;
    bi = 8 * b + r;
    bj = 8 * b + r + (u - before);
  }

  const int tid = threadIdx.x;
  const int lane = tid & 63;
  const int wid = tid >> 6;
  const int wr = wid >> 2, wc = wid & 3;
  const int lr = lane & 15;
  const int kgrp = (lane >> 4) << 4;       // frag k-group byte
  const int kswz = (lane & 7) << 4;        // read-side XOR (row&7 == lane&7)
  const char* zb = (const char*)zn;
  const int arow0 = bi * 256, brow0 = bj * 256;

  // staging geometry: 4 chunks/thread per 32KB op-tile; linear LDS dest,
  // inverse-swizzled global source (rule #21)
  int srow[4], scol[4];
#pragma unroll
  for (int cc = 0; cc < 4; ++cc) {
    int lo = cc * 8192 + wid * 1024 + lane * 16;  // linear LDS byte offset
    srow[cc] = lo >> 7;                           // tile row (128 B/row)
    scol[cc] = (lo & 127) ^ ((srow[cc] & 7) << 4);
  }

#define STAGE_OP(buf, opoff, rowbase, tau) do {                                          \
    _Pragma("unroll")                                                                    \
    for (int cc = 0; cc < 4; ++cc) {                                                     \
      char* _d = smem + (buf) * 65536 + (opoff) + cc * 8192 + wid * 1024;                \
      const char* _s = zb + (size_t)((rowbase) + srow[cc]) * 1024 + (tau) * 128 + scol[cc]; \
      __builtin_amdgcn_global_load_lds((__attribute__((address_space(1))) void*)_s,      \
          (__attribute__((address_space(3))) void*)_d, 16, 0, 0);                        \
    }                                                                                    \
  } while (0)

#define WAIT_LGKM0() do { asm volatile("s_waitcnt lgkmcnt(0)" ::: "memory"); \
    __builtin_amdgcn_sched_barrier(0); } while (0)

  float4v acc[8][4];
#pragma unroll
  for (int m = 0; m < 8; ++m)
#pragma unroll
    for (int n = 0; n < 4; ++n) acc[m][n] = {0.f, 0.f, 0.f, 0.f};

  // prologue: stage tile 0 (A+B), drain, sync
  STAGE_OP(0, 0, arow0, 0);
  STAGE_OP(0, 32768, brow0, 0);
  asm volatile("s_waitcnt vmcnt(0)" ::: "memory");
  __builtin_amdgcn_sched_barrier(0);
  __builtin_amdgcn_s_barrier();

  for (int t = 0; t < NT; ++t) {
    const int c = t & 1;
    const char* ab = smem + c * 65536;
    const char* bb = ab + 32768;
    short8v a[2][4], b2[2][4];

    // ---- ph0: read A-lo + B n01; stage A(t+1) ----
#pragma unroll
    for (int kk = 0; kk < 2; ++kk) {
      int ko = kk * 64 + kgrp;
#pragma unroll
      for (int mm = 0; mm < 4; ++mm)
        a[kk][mm] = *(const short8v*)(ab + (wr * 128 + mm * 16 + lr) * 128 + (ko ^ kswz));
      b2[kk][0] = *(const short8v*)(bb + (wc * 64 + lr) * 128 + (ko ^ kswz));
      b2[kk][1] = *(const short8v*)(bb + (wc * 64 + 16 + lr) * 128 + (ko ^ kswz));
    }
    if (t + 1 < NT) STAGE_OP(c ^ 1, 0, arow0, t + 1);
    __builtin_amdgcn_s_barrier();
    WAIT_LGKM0();
    __builtin_amdgcn_s_setprio(1);
#pragma unroll
    for (int kk = 0; kk < 2; ++kk)
#pragma unroll
      for (int mm = 0; mm < 4; ++mm)
#pragma unroll
        for (int n = 0; n < 2; ++n)
          acc[mm][n] = __builtin_amdgcn_mfma_f32_16x16x32_bf16(a[kk][mm], b2[kk][n], acc[mm][n], 0, 0, 0);
    __builtin_amdgcn_s_setprio(0);
    __builtin_amdgcn_s_barrier();

    // ---- ph1: read B n23; stage B(t+1) ----
#pragma unroll
    for (int kk = 0; kk < 2; ++kk) {
      int ko = kk * 64 + kgrp;
      b2[kk][2] = *(const short8v*)(bb + (wc * 64 + 32 + lr) * 128 + (ko ^ kswz));
      b2[kk][3] = *(const short8v*)(bb + (wc * 64 + 48 + lr) * 128 + (ko ^ kswz));
    }
    if (t + 1 < NT) STAGE_OP(c ^ 1, 32768, brow0, t + 1);
    __builtin_amdgcn_s_barrier();
    WAIT_LGKM0();
    __builtin_amdgcn_s_setprio(1);
#pragma unroll
    for (int kk = 0; kk < 2; ++kk)
#pragma unroll
      for (int mm = 0; mm < 4; ++mm)
#pragma unroll
        for (int n = 0; n < 2; ++n)
          acc[mm][2 + n] = __builtin_amdgcn_mfma_f32_16x16x32_bf16(a[kk][mm], b2[kk][2 + n], acc[mm][2 + n], 0, 0, 0);
    __builtin_amdgcn_s_setprio(0);
    __builtin_amdgcn_s_barrier();

    // ---- ph2: read A-hi ----
#pragma unroll
    for (int kk = 0; kk < 2; ++kk) {
      int ko = kk * 64 + kgrp;
#pragma unroll
      for (int mm = 0; mm < 4; ++mm)
        a[kk][mm] = *(const short8v*)(ab + (wr * 128 + 64 + mm * 16 + lr) * 128 + (ko ^ kswz));
    }
    __builtin_amdgcn_s_barrier();
    WAIT_LGKM0();
    __builtin_amdgcn_s_setprio(1);
#pragma unroll
    for (int kk = 0; kk < 2; ++kk)
#pragma unroll
      for (int mm = 0; mm < 4; ++mm)
#pragma unroll
        for (int n = 0; n < 2; ++n)
          acc[4 + mm][2 + n] = __builtin_amdgcn_mfma_f32_16x16x32_bf16(a[kk][mm], b2[kk][2 + n], acc[4 + mm][2 + n], 0, 0, 0);
    __builtin_amdgcn_s_setprio(0);
    __builtin_amdgcn_s_barrier();

    // ---- ph3: MFMA only (regs); drain t+1's stages, flip buffers ----
    __builtin_amdgcn_s_setprio(1);
#pragma unroll
    for (int kk = 0; kk < 2; ++kk)
#pragma unroll
      for (int mm = 0; mm < 4; ++mm)
#pragma unroll
        for (int n = 0; n < 2; ++n)
          acc[4 + mm][n] = __builtin_amdgcn_mfma_f32_16x16x32_bf16(a[kk][mm], b2[kk][n], acc[4 + mm][n], 0, 0, 0);
    __builtin_amdgcn_s_setprio(0);
    if (t + 1 < NT) {
      asm volatile("s_waitcnt vmcnt(0)" ::: "memory");
      __builtin_amdgcn_sched_barrier(0);
    }
    __builtin_amdgcn_s_barrier();
  }
#undef STAGE_OP
#undef WAIT_LGKM0

  // epilogue: e = exp(2*dot - 2) = exp2(C*dot - C)
  const float C = 2.88539008177792681f;
  float rowacc[8][4];
  float colacc[4] = {0.f, 0.f, 0.f, 0.f};
#pragma unroll
  for (int m = 0; m < 8; ++m)
#pragma unroll
    for (int r = 0; r < 4; ++r) rowacc[m][r] = 0.f;
#pragma unroll
  for (int m = 0; m < 8; ++m)
#pragma unroll
    for (int n = 0; n < 4; ++n)
#pragma unroll
      for (int r = 0; r < 4; ++r) {
        float e = exp2f(fmaf(acc[m][n][r], C, -C));
        rowacc[m][r] += e;
        colacc[n] += e;
      }

  // row sums: reduce over columns (lane&15); one atomic per row per wave
#pragma unroll
  for (int m = 0; m < 8; ++m)
#pragma unroll
    for (int r = 0; r < 4; ++r) {
      float v = rowacc[m][r];
      v += __shfl_xor(v, 1);
      v += __shfl_xor(v, 2);
      v += __shfl_xor(v, 4);
      v += __shfl_xor(v, 8);
      if ((lane & 15) == 0)
        atomicAdd(&rowsum[arow0 + wr * 128 + m * 16 + ((lane >> 4) << 2) + r], v);
    }
  // col sums (symmetric contribution), off-diagonal tiles only
  if (bi != bj) {
#pragma unroll
    for (int n = 0; n < 4; ++n) {
      float v = colacc[n];
      v += __shfl_xor(v, 16);
      v += __shfl_xor(v, 32);
      if (lane < 16) atomicAdd(&rowsum[brow0 + wc * 64 + n * 16 + lane], v);
    }
  }
}

// ---------- finalize: loss = (sum(2 + log rowsum) - sum tpart) / 8192 ----------
__global__ __launch_bounds__(256) void k_finalize(const float* __restrict__ rowsum,
                                                  const float* __restrict__ tpart,
                                                  float* __restrict__ out) {
  int t = threadIdx.x;
  float acc = 0.f;
  for (int i = t; i < N2; i += 256) acc += 2.0f + logf(rowsum[i]);
  for (int i = t; i < B_ROWS; i += 256) acc -= tpart[i];
#pragma unroll
  for (int off = 32; off; off >>= 1) acc += __shfl_down(acc, off, 64);
  __shared__ float wsum[4];
  if ((t & 63) == 0) wsum[t >> 6] = acc;
  __syncthreads();
  if (t == 0) out[0] = (wsum[0] + wsum[1] + wsum[2] + wsum[3]) * (1.0f / (float)N2);
}

extern "C" void kernel_launch(void* const* d_in, const int* in_sizes, int n_in,
                              void* d_out, int out_size, void* d_ws, size_t ws_size,
                              hipStream_t stream) {
  const float* f1 = (const float*)d_in[0];
  const float* f2 = (const float*)d_in[1];
  float* out = (float*)d_out;
  char* ws = (char*)d_ws;

  uint4* zn_w = (uint4*)ws;                              // 8 MB bf16 zn
  unsigned short* zn = (unsigned short*)ws;
  float* rowsum = (float*)(ws + (size_t)N2 * DD * 2);    // 32 KB
  float* tpart = rowsum + N2;                            // 16 KB

  k_norm_tgt<<<B_ROWS / 4, 256, 0, stream>>>(f1, f2, zn_w, tpart, rowsum);
  k_gemm_expsum<<<NTRI, 512, 0, stream>>>(zn, rowsum);
  k_finalize<<<1, 256, 0, stream>>>(rowsum, tpart, out);
}

// Round 8
// 80.386 us; speedup vs baseline: 1.1518x; 1.1518x over previous
//
#include <hip/hip_runtime.h>
#include <hip/hip_bf16.h>

#define B_ROWS 4096
#define N2 8192
#define DD 512
#define NB 64        // 8192/128 tile-blocks per dim
#define NTRI 2080    // NB*(NB+1)/2
#define NT 8         // DD/64 K-tiles

typedef __attribute__((ext_vector_type(8))) short short8v;
typedef __attribute__((ext_vector_type(4))) float float4v;

__device__ inline unsigned int f2bf(float f) {
  unsigned int u = __float_as_uint(f);
  u += 0x7fffu + ((u >> 16) & 1u);
  return u >> 16;
}

// ---------- normalize + targets + rowsum-zero, one wave per row-pair ----------
__global__ __launch_bounds__(256) void k_norm_tgt(const float* __restrict__ f1,
                                                  const float* __restrict__ f2,
                                                  uint4* __restrict__ zn,
                                                  float* __restrict__ tpart,
                                                  float* __restrict__ rowsum) {
  int w = threadIdx.x >> 6, lane = threadIdx.x & 63;
  int j = blockIdx.x * 4 + w;  // pair index 0..4095
  const float4* s1 = (const float4*)(f1 + (size_t)j * DD);
  const float4* s2 = (const float4*)(f2 + (size_t)j * DD);
  float4 a0 = s1[lane * 2], a1 = s1[lane * 2 + 1];
  float4 b0 = s2[lane * 2], b1 = s2[lane * 2 + 1];
  float ss1 = a0.x * a0.x + a0.y * a0.y + a0.z * a0.z + a0.w * a0.w +
              a1.x * a1.x + a1.y * a1.y + a1.z * a1.z + a1.w * a1.w;
  float ss2 = b0.x * b0.x + b0.y * b0.y + b0.z * b0.z + b0.w * b0.w +
              b1.x * b1.x + b1.y * b1.y + b1.z * b1.z + b1.w * b1.w;
  float ab = a0.x * b0.x + a0.y * b0.y + a0.z * b0.z + a0.w * b0.w +
             a1.x * b1.x + a1.y * b1.y + a1.z * b1.z + a1.w * b1.w;
#pragma unroll
  for (int o = 1; o < 64; o <<= 1) {
    ss1 += __shfl_xor(ss1, o, 64);
    ss2 += __shfl_xor(ss2, o, 64);
    ab += __shfl_xor(ab, o, 64);
  }
  float inv1 = 1.0f / fmaxf(sqrtf(ss1), 1e-8f);
  float inv2 = 1.0f / fmaxf(sqrtf(ss2), 1e-8f);
  uint4 p;
  p.x = f2bf(a0.x * inv1) | (f2bf(a0.y * inv1) << 16);
  p.y = f2bf(a0.z * inv1) | (f2bf(a0.w * inv1) << 16);
  p.z = f2bf(a1.x * inv1) | (f2bf(a1.y * inv1) << 16);
  p.w = f2bf(a1.z * inv1) | (f2bf(a1.w * inv1) << 16);
  zn[(size_t)j * (DD / 8) + lane] = p;
  p.x = f2bf(b0.x * inv2) | (f2bf(b0.y * inv2) << 16);
  p.y = f2bf(b0.z * inv2) | (f2bf(b0.w * inv2) << 16);
  p.z = f2bf(b1.x * inv2) | (f2bf(b1.y * inv2) << 16);
  p.w = f2bf(b1.z * inv2) | (f2bf(b1.w * inv2) << 16);
  zn[(size_t)(B_ROWS + j) * (DD / 8) + lane] = p;
  if (lane == 0) tpart[j] = 2.0f + 2.0f * ab * inv1 * inv2;  // logit[i,i] + logit[i,i+B]
  if (threadIdx.x < 8) rowsum[blockIdx.x * 8 + threadIdx.x] = 0.f;  // 1024*8 = 8192
}

// ---------- main: upper-triangular 128x128 tiles of S = zn.zn^T ----------
// Band-major order (L2-resident B window) + XCD-chunked swizzle.
// Single-buffer 32KB LDS -> 4 blocks/CU: cross-block TLP hides stage latency.
__global__ __launch_bounds__(256, 4) void k_gemm_expsum(const unsigned short* __restrict__ zn,
                                                        float* __restrict__ rowsum) {
  __shared__ __align__(16) char smem[32768];  // [A 16KB | B 16KB], single buffer

  // XCD-chunked swizzle (2080 % 8 == 0): each XCD gets a contiguous band-major range
  int g = (blockIdx.x & 7) * (NTRI / 8) + (blockIdx.x >> 3);

  // band-major decode: band b covers bj in [8b, 8b+8), bi in [0, bj].
  // off(b) = 32*b*b + 4*b; full-rows part (bi < 8b) is bi-major, then 8x8 upper-tri.
  int b = 7;
  while (32 * b * b + 4 * b > g) --b;
  int tp = g - (32 * b * b + 4 * b);
  int bi, bj;
  if (tp < 64 * b) {
    bi = tp >> 3;                 // A panel reused for 8 consecutive tiles
    bj = 8 * b + (tp & 7);        // B window: 8 panels (1 MB), L2-hot
  } else {
    int u = tp - 64 * b;          // 0..35: upper-tri of the 8x8 diagonal block
    int r = 0;
    while ((r + 1) * 8 - (r * (r + 1)) / 2 <= u) ++r;
    int before = r * 8 - ((r - 1) * r) / 2;
    bi = 8 * b + r;
    bj = 8 * b + r + (u - before);
  }

  const int tid = threadIdx.x;
  const int lane = tid & 63, w = tid >> 6;
  const int wr = w >> 1, wc = w & 1;
  const char* zb = (const char*)zn;
  const int arow0 = bi * 128, brow0 = bj * 128;

  // staging geometry (hoisted): 4 chunks/wave, 2 loads each (A,B)
  int sbase[4], scb[4], srow[4];
#pragma unroll
  for (int cc = 0; cc < 4; ++cc) {
    sbase[cc] = (w * 4 + cc) << 10;            // LDS byte base within a 16KB op-tile
    int lo = sbase[cc] + lane * 16;            // linear LDS dest = base + lane*16
    srow[cc] = lo >> 7;                        // tile row (128 B/row)
    scb[cc] = (lo & 127) ^ ((srow[cc] & 7) << 4);  // pre-swizzled SOURCE col (rule #21)
  }

  float4v acc[4][4];
#pragma unroll
  for (int m = 0; m < 4; ++m)
#pragma unroll
    for (int n = 0; n < 4; ++n) acc[m][n] = {0.f, 0.f, 0.f, 0.f};

  for (int t = 0; t < NT; ++t) {
    // stage tile t (A+B): 8 x global_load_lds width-16 per thread
#pragma unroll
    for (int cc = 0; cc < 4; ++cc) {
      const char* ga = zb + (size_t)(arow0 + srow[cc]) * 1024 + t * 128 + scb[cc];
      const char* gb = zb + (size_t)(brow0 + srow[cc]) * 1024 + t * 128 + scb[cc];
      __builtin_amdgcn_global_load_lds((__attribute__((address_space(1))) void*)ga,
          (__attribute__((address_space(3))) void*)(smem + sbase[cc]), 16, 0, 0);
      __builtin_amdgcn_global_load_lds((__attribute__((address_space(1))) void*)gb,
          (__attribute__((address_space(3))) void*)(smem + 16384 + sbase[cc]), 16, 0, 0);
    }
    __syncthreads();  // drains vmcnt; stage latency hidden by other resident blocks

    const char* ab = smem;
    const char* bb = smem + 16384;
#pragma unroll
    for (int kk = 0; kk < 2; ++kk) {
      short8v a[4], bf[4];
      int koff = kk * 64 + ((lane >> 4) << 4);
#pragma unroll
      for (int m = 0; m < 4; ++m) {
        int row = wr * 64 + m * 16 + (lane & 15);
        a[m] = *(const short8v*)(ab + row * 128 + (koff ^ ((row & 7) << 4)));
      }
#pragma unroll
      for (int n = 0; n < 4; ++n) {
        int row = wc * 64 + n * 16 + (lane & 15);
        bf[n] = *(const short8v*)(bb + row * 128 + (koff ^ ((row & 7) << 4)));
      }
#pragma unroll
      for (int m = 0; m < 4; ++m)
#pragma unroll
        for (int n = 0; n < 4; ++n)
          acc[m][n] = __builtin_amdgcn_mfma_f32_16x16x32_bf16(a[m], bf[n], acc[m][n], 0, 0, 0);
    }
    if (t + 1 < NT) __syncthreads();  // all reads done before next stage overwrites
  }

  // epilogue: e = exp(2*dot - 2) = exp2(C*dot - C)
  const float C = 2.88539008177792681f;
  float rowacc[4][4];
  float colacc[4] = {0.f, 0.f, 0.f, 0.f};
#pragma unroll
  for (int m = 0; m < 4; ++m)
#pragma unroll
    for (int r = 0; r < 4; ++r) rowacc[m][r] = 0.f;
#pragma unroll
  for (int m = 0; m < 4; ++m)
#pragma unroll
    for (int n = 0; n < 4; ++n)
#pragma unroll
      for (int r = 0; r < 4; ++r) {
        float e = exp2f(fmaf(acc[m][n][r], C, -C));
        rowacc[m][r] += e;
        colacc[n] += e;
      }

  // row sums: reduce over columns (lane&15); one atomic per row per wave
#pragma unroll
  for (int m = 0; m < 4; ++m)
#pragma unroll
    for (int r = 0; r < 4; ++r) {
      float v = rowacc[m][r];
      v += __shfl_xor(v, 1);
      v += __shfl_xor(v, 2);
      v += __shfl_xor(v, 4);
      v += __shfl_xor(v, 8);
      if ((lane & 15) == 0)
        atomicAdd(&rowsum[arow0 + wr * 64 + m * 16 + ((lane >> 4) << 2) + r], v);
    }
  // col sums (symmetric contribution), off-diagonal tiles only
  if (bi != bj) {
#pragma unroll
    for (int n = 0; n < 4; ++n) {
      float v = colacc[n];
      v += __shfl_xor(v, 16);
      v += __shfl_xor(v, 32);
      if (lane < 16) atomicAdd(&rowsum[brow0 + wc * 64 + n * 16 + lane], v);
    }
  }
}

// ---------- finalize: loss = (sum(2 + log rowsum) - sum tpart) / 8192 ----------
__global__ __launch_bounds__(256) void k_finalize(const float* __restrict__ rowsum,
                                                  const float* __restrict__ tpart,
                                                  float* __restrict__ out) {
  int t = threadIdx.x;
  float acc = 0.f;
  for (int i = t; i < N2; i += 256) acc += 2.0f + logf(rowsum[i]);
  for (int i = t; i < B_ROWS; i += 256) acc -= tpart[i];
#pragma unroll
  for (int off = 32; off; off >>= 1) acc += __shfl_down(acc, off, 64);
  __shared__ float wsum[4];
  if ((t & 63) == 0) wsum[t >> 6] = acc;
  __syncthreads();
  if (t == 0) out[0] = (wsum[0] + wsum[1] + wsum[2] + wsum[3]) * (1.0f / (float)N2);
}

extern "C" void kernel_launch(void* const* d_in, const int* in_sizes, int n_in,
                              void* d_out, int out_size, void* d_ws, size_t ws_size,
                              hipStream_t stream) {
  const float* f1 = (const float*)d_in[0];
  const float* f2 = (const float*)d_in[1];
  float* out = (float*)d_out;
  char* ws = (char*)d_ws;

  uint4* zn_w = (uint4*)ws;                              // 8 MB bf16 zn
  unsigned short* zn = (unsigned short*)ws;
  float* rowsum = (float*)(ws + (size_t)N2 * DD * 2);    // 32 KB
  float* tpart = rowsum + N2;                            // 16 KB

  k_norm_tgt<<<B_ROWS / 4, 256, 0, stream>>>(f1, f2, zn_w, tpart, rowsum);
  k_gemm_expsum<<<NTRI, 256, 0, stream>>>(zn, rowsum);
  k_finalize<<<1, 256, 0, stream>>>(rowsum, tpart, out);
}